// Round 7
// baseline (421.338 us; speedup 1.0000x reference)
//
#include <hip/hip_runtime.h>

// EdgeLoss: mean |sobel_mag(gray(pred)) - sobel_mag(gray(target))|
// pred/target: (32, 3, 512, 512) fp32, output: scalar fp32.
//
// R8 post-mortem -> unifying model: per-CU L1/vector-path throughput is
// ~10.2 B/cyc/CU (256 CU x 10.2 x 2.4GHz = 6.3 TB/s = the "HBM" ceiling),
// residency-independent (warm == cold in every round). Floor = requested
// bytes / 6.3 TB/s: R2 240MB->38us(+serial LDS/VALU = 87), R8 906MB->145
// (measured 132). Lever: minimal requested bytes (R2's tile, 1.19x) AND
// overlap of LDS+VALU under the VMEM stream (R2 barrier-serialized them).
//
// R9: persistent blocks, 4 vertical tiles each, double-buffered LDS +
// T14 issue-early/write-late: per tile { barrier; issue next tile's 18
// float4 loads (clamped addresses, no branches); compute current tile
// from LDS (~750cyc, covers latency); gray+write other buffer (vmcnt
// wait lands here, already elapsed) }. Loads are issued AFTER the
// barrier so its vmcnt-drain never touches them. sched_barrier(0)
// fences pin loads above compute and gray below it.

#define BATCH 32
#define HH 512
#define WW 512
#define TX 64
#define TY 32
#define NT 4                      // vertical tiles per block
#define LDS_W 72                  // staged floats per row (x0-4 .. x0+67)
#define LDS_W4 18
#define LDS_ROWS 34               // y0-1 .. y0+32
#define SLOTS (LDS_ROWS * LDS_W4) // 612 float4 slots per image
#define IMG ((size_t)HH * WW)

__global__ void zero_out_kernel(float* out) { out[0] = 0.0f; }

__global__ __launch_bounds__(256, 4) void edge_loss_kernel(
    const float* __restrict__ pred,
    const float* __restrict__ target,
    float* __restrict__ out)
{
    __shared__ float gp[2][LDS_ROWS * LDS_W];
    __shared__ float gt[2][LDS_ROWS * LDS_W];
    __shared__ float wsum[4];

    const int tid = threadIdx.x;
    const int x0  = blockIdx.x * TX;
    const int tt0 = blockIdx.y * NT;         // first tile row-index
    const int b   = blockIdx.z;

    const float* pbase = pred   + (size_t)b * 3 * IMG;
    const float* tbase = target + (size_t)b * 3 * IMG;

    // ---- per-trip slot geometry (x part invariant across tiles) ----
    int  rowv[3], gxc[3];
    bool okx[3], act[3];
    #pragma unroll
    for (int tr = 0; tr < 3; ++tr) {
        const int i = tid + tr * 256;
        const int r = i / LDS_W4;
        const int c = i - r * LDS_W4;
        rowv[tr] = r;
        const int gx = x0 - 4 + 4 * c;
        okx[tr] = (gx >= 0) && (gx <= WW - 4);
        gxc[tr] = min(max(gx, 0), WW - 4);   // stays %4==0
        act[tr] = (i < SLOTS);               // trip 2: only tid<100
    }

    float4 Lp[3][3], Lt[3][3];   // [trip][channel] — unrolled const indexing
    bool   vld[3];

    // Issue 18 float4 loads for the tile whose first output row is y0_.
    // Addresses are clamped in-bounds; validity selected at write time.
#define STAGE_LOAD(y0_) do {                                            \
    _Pragma("unroll")                                                   \
    for (int tr = 0; tr < 3; ++tr) {                                    \
        const int gy  = (y0_) - 1 + rowv[tr];                           \
        vld[tr] = okx[tr] && (gy >= 0) && (gy < HH);                    \
        const int gyc = min(max(gy, 0), HH - 1);                        \
        const size_t o = (size_t)gyc * WW + gxc[tr];                    \
        if (tr < 2 || act[tr]) {                                        \
            Lp[tr][0] = *(const float4*)(pbase + o);                    \
            Lp[tr][1] = *(const float4*)(pbase + o + IMG);              \
            Lp[tr][2] = *(const float4*)(pbase + o + 2 * IMG);          \
            Lt[tr][0] = *(const float4*)(tbase + o);                    \
            Lt[tr][1] = *(const float4*)(tbase + o + IMG);              \
            Lt[tr][2] = *(const float4*)(tbase + o + 2 * IMG);          \
        }                                                               \
    }                                                                   \
} while (0)

    // Gray-convert the held registers and write LDS buffer BUF.
#define STAGE_WRITE(BUF) do {                                           \
    float4* gpw = (float4*)gp[BUF];                                     \
    float4* gtw = (float4*)gt[BUF];                                     \
    _Pragma("unroll")                                                   \
    for (int tr = 0; tr < 3; ++tr) {                                    \
        const int i = tid + tr * 256;                                   \
        if (tr < 2 || act[tr]) {                                        \
            float4 vp = make_float4(0.f, 0.f, 0.f, 0.f);                \
            float4 vt = make_float4(0.f, 0.f, 0.f, 0.f);                \
            if (vld[tr]) {                                              \
                vp.x = 0.299f*Lp[tr][0].x + 0.587f*Lp[tr][1].x + 0.114f*Lp[tr][2].x; \
                vp.y = 0.299f*Lp[tr][0].y + 0.587f*Lp[tr][1].y + 0.114f*Lp[tr][2].y; \
                vp.z = 0.299f*Lp[tr][0].z + 0.587f*Lp[tr][1].z + 0.114f*Lp[tr][2].z; \
                vp.w = 0.299f*Lp[tr][0].w + 0.587f*Lp[tr][1].w + 0.114f*Lp[tr][2].w; \
                vt.x = 0.299f*Lt[tr][0].x + 0.587f*Lt[tr][1].x + 0.114f*Lt[tr][2].x; \
                vt.y = 0.299f*Lt[tr][0].y + 0.587f*Lt[tr][1].y + 0.114f*Lt[tr][2].y; \
                vt.z = 0.299f*Lt[tr][0].z + 0.587f*Lt[tr][1].z + 0.114f*Lt[tr][2].z; \
                vt.w = 0.299f*Lt[tr][0].w + 0.587f*Lt[tr][1].w + 0.114f*Lt[tr][2].w; \
            }                                                           \
            gpw[i] = vp;                                                \
            gtw[i] = vt;                                                \
        }                                                               \
    }                                                                   \
} while (0)

    int   cur  = 0;
    float lsum = 0.0f;

    // ---- prologue: stage tile 0 into buffer 0 (one full-latency wait) ----
    STAGE_LOAD(tt0 * TY);
    STAGE_WRITE(0);

    for (int t = 0; t < NT; ++t) {
        __syncthreads();                       // buf[cur] writes visible
        const bool have = (t + 1 < NT);
        if (have) STAGE_LOAD((tt0 + t + 1) * TY);   // issued AFTER barrier
        __builtin_amdgcn_sched_barrier(0);          // loads stay above compute

        // ---- compute tile t from buf[cur] (identical to R2, proven) ----
        {
            const float* gpc = gp[cur];
            const float* gtc = gt[cur];
            const int tx = tid & 63;
            const int ty = tid >> 6;
            #pragma unroll
            for (int ii = 0; ii < TY / 4; ++ii) {
                const int ry = ty + 4 * ii;
                const float* cp = &gpc[ry * LDS_W + tx + 3];
                const float* ct = &gtc[ry * LDS_W + tx + 3];

                float p00 = cp[0],         p01 = cp[1],             p02 = cp[2];
                float p10 = cp[LDS_W],                              p12 = cp[LDS_W + 2];
                float p20 = cp[2*LDS_W],   p21 = cp[2*LDS_W + 1],   p22 = cp[2*LDS_W + 2];
                float ex = (p02 - p00) + 2.0f * (p12 - p10) + (p22 - p20);
                float ey = (p20 - p00) + 2.0f * (p21 - p01) + (p22 - p02);
                float ep = sqrtf(ex * ex + ey * ey);

                float t00 = ct[0],         t01 = ct[1],             t02 = ct[2];
                float t10 = ct[LDS_W],                              t12 = ct[LDS_W + 2];
                float t20 = ct[2*LDS_W],   t21 = ct[2*LDS_W + 1],   t22 = ct[2*LDS_W + 2];
                float fx = (t02 - t00) + 2.0f * (t12 - t10) + (t22 - t20);
                float fy = (t20 - t00) + 2.0f * (t21 - t01) + (t22 - t02);
                float et = sqrtf(fx * fx + fy * fy);

                lsum += fabsf(ep - et);
            }
        }
        __builtin_amdgcn_sched_barrier(0);     // gray/write stay below compute

        if (have) STAGE_WRITE(cur ^ 1);        // vmcnt wait lands here
        cur ^= 1;
    }

    // ---- reduce: wave shuffle -> cross-wave LDS -> one atomic per block ----
    #pragma unroll
    for (int off = 32; off > 0; off >>= 1)
        lsum += __shfl_down(lsum, off, 64);

    if ((tid & 63) == 0) wsum[tid >> 6] = lsum;
    __syncthreads();
    if (tid == 0) {
        const float s = wsum[0] + wsum[1] + wsum[2] + wsum[3];
        const float inv_n = 1.0f / ((float)BATCH * HH * WW);
        atomicAdd(out, s * inv_n);
    }
}

extern "C" void kernel_launch(void* const* d_in, const int* in_sizes, int n_in,
                              void* d_out, int out_size, void* d_ws, size_t ws_size,
                              hipStream_t stream) {
    const float* pred   = (const float*)d_in[0];
    const float* target = (const float*)d_in[1];
    float* out = (float*)d_out;

    // d_out is poisoned 0xAA before every timed launch -> zero it on-stream.
    zero_out_kernel<<<1, 1, 0, stream>>>(out);

    // 8 x-tiles x 4 tile-groups (NT=4 vertical tiles each) x 32 images
    // = 1024 blocks = exactly 4 blocks/CU, 16 waves/CU, 156KB LDS/CU.
    dim3 grid(WW / TX, (HH / TY) / NT, BATCH);
    edge_loss_kernel<<<grid, 256, 0, stream>>>(pred, target, out);
}

// Round 9
// 417.023 us; speedup vs baseline: 1.0103x; 1.0103x over previous
//
#include <hip/hip_runtime.h>

// EdgeLoss: mean |sobel_mag(gray(pred)) - sobel_mag(gray(target))|
// pred/target: (32, 3, 512, 512) fp32, output: scalar fp32.
//
// R9 post-mortem: WRITE_SIZE=462MB + FETCH=423MB + VGPR=64 + VALUBusy 5.8%
// -> the Lp[3][3]/Lt[3][3] staging arrays went to SCRATCH (rule #20: the
// _Pragma-in-macro unroll didn't take; runtime-indexed / conditionally
// written arrays -> localMem). 290us was a spill benchmark, not a test of
// the overlap theory. Phase model corroborated elsewhere: R2 87us = sum of
// pipe times (convoy effect); R8 = 6.9 TB/s of requested bytes when issue
// is continuous. Floor for 1.19x-halo tiling = 240MB / 6.9 = ~35us.
//
// R10 = R9 with spill-proof codegen: hand-unrolled staging into NAMED
// float4 registers (no arrays, no trip loops). Trips 0/1 unconditional,
// trip 2 guarded (named conditional assignment = phi in VGPR, fine).
// Hold = 18 float4 = 72 VGPR across compute; budget 128 at 4 waves/EU.
// Per tile: { barrier; issue 18 loads for t+1; compute tile t from LDS
// (~2000cyc, covers latency); gray+write buf^1 (vmcnt lands here) }.
//
// R11: identical resubmit — R10 never ran (GPUAcquisitionTimeout).

#define BATCH 32
#define HH 512
#define WW 512
#define TX 64
#define TY 32
#define NT 4                      // vertical tiles per persistent block
#define LDS_W 72                  // staged floats per row (x0-4 .. x0+67)
#define LDS_W4 18
#define LDS_ROWS 34               // y0-1 .. y0+32
#define SLOTS (LDS_ROWS * LDS_W4) // 612 float4 slots per image
#define IMG ((size_t)HH * WW)

__global__ void zero_out_kernel(float* out) { out[0] = 0.0f; }

__global__ __launch_bounds__(256, 4) void edge_loss_kernel(
    const float* __restrict__ pred,
    const float* __restrict__ target,
    float* __restrict__ out)
{
    __shared__ float gp[2][LDS_ROWS * LDS_W];
    __shared__ float gt[2][LDS_ROWS * LDS_W];
    __shared__ float wsum[4];

    const int tid = threadIdx.x;
    const int x0  = blockIdx.x * TX;
    const int tt0 = blockIdx.y * NT;
    const int b   = blockIdx.z;

    const float* pbase = pred   + (size_t)b * 3 * IMG;
    const float* tbase = target + (size_t)b * 3 * IMG;

    // ---- per-trip slot geometry (x part invariant across tiles) ----
    const int  i0 = tid, i1 = tid + 256, i2 = tid + 512;
    const int  row0 = i0 / LDS_W4, c0_ = i0 - row0 * LDS_W4;
    const int  row1 = i1 / LDS_W4, c1_ = i1 - row1 * LDS_W4;
    const int  row2 = i2 / LDS_W4, c2_ = i2 - row2 * LDS_W4;
    const bool act2 = (i2 < SLOTS);

    const int gx0 = x0 - 4 + 4 * c0_;
    const int gx1 = x0 - 4 + 4 * c1_;
    const int gx2 = x0 - 4 + 4 * c2_;
    const bool okx0 = (gx0 >= 0) & (gx0 <= WW - 4);
    const bool okx1 = (gx1 >= 0) & (gx1 <= WW - 4);
    const bool okx2 = (gx2 >= 0) & (gx2 <= WW - 4);
    const int gxc0 = min(max(gx0, 0), WW - 4);
    const int gxc1 = min(max(gx1, 0), WW - 4);
    const int gxc2 = min(max(gx2, 0), WW - 4);

    // ---- named staging registers: 18 float4, NO arrays (spill-proof) ----
    float4 Ap_r, Ap_g, Ap_b, At_r, At_g, At_b;   // trip 0
    float4 Bp_r, Bp_g, Bp_b, Bt_r, Bt_g, Bt_b;   // trip 1
    float4 Cp_r, Cp_g, Cp_b, Ct_r, Ct_g, Ct_b;   // trip 2
    bool v0, v1, v2;

#define STAGE_LOAD(Y0_) do {                                              \
    int gy_; size_t o_;                                                   \
    gy_ = (Y0_) - 1 + row0;                                               \
    v0 = okx0 & (gy_ >= 0) & (gy_ < HH);                                  \
    o_ = (size_t)min(max(gy_, 0), HH - 1) * WW + gxc0;                    \
    Ap_r = *(const float4*)(pbase + o_);                                  \
    Ap_g = *(const float4*)(pbase + o_ + IMG);                            \
    Ap_b = *(const float4*)(pbase + o_ + 2 * IMG);                        \
    At_r = *(const float4*)(tbase + o_);                                  \
    At_g = *(const float4*)(tbase + o_ + IMG);                            \
    At_b = *(const float4*)(tbase + o_ + 2 * IMG);                        \
    gy_ = (Y0_) - 1 + row1;                                               \
    v1 = okx1 & (gy_ >= 0) & (gy_ < HH);                                  \
    o_ = (size_t)min(max(gy_, 0), HH - 1) * WW + gxc1;                    \
    Bp_r = *(const float4*)(pbase + o_);                                  \
    Bp_g = *(const float4*)(pbase + o_ + IMG);                            \
    Bp_b = *(const float4*)(pbase + o_ + 2 * IMG);                        \
    Bt_r = *(const float4*)(tbase + o_);                                  \
    Bt_g = *(const float4*)(tbase + o_ + IMG);                            \
    Bt_b = *(const float4*)(tbase + o_ + 2 * IMG);                        \
    gy_ = (Y0_) - 1 + row2;                                               \
    v2 = act2 & okx2 & (gy_ >= 0) & (gy_ < HH);                           \
    o_ = (size_t)min(max(gy_, 0), HH - 1) * WW + gxc2;                    \
    if (act2) {                                                           \
        Cp_r = *(const float4*)(pbase + o_);                              \
        Cp_g = *(const float4*)(pbase + o_ + IMG);                        \
        Cp_b = *(const float4*)(pbase + o_ + 2 * IMG);                    \
        Ct_r = *(const float4*)(tbase + o_);                              \
        Ct_g = *(const float4*)(tbase + o_ + IMG);                        \
        Ct_b = *(const float4*)(tbase + o_ + 2 * IMG);                    \
    }                                                                     \
} while (0)

#define GRAY4S(dst, r4, g4, b4, valid) do {                               \
    float4 v_ = make_float4(0.f, 0.f, 0.f, 0.f);                          \
    if (valid) {                                                          \
        v_.x = 0.299f * r4.x + 0.587f * g4.x + 0.114f * b4.x;             \
        v_.y = 0.299f * r4.y + 0.587f * g4.y + 0.114f * b4.y;             \
        v_.z = 0.299f * r4.z + 0.587f * g4.z + 0.114f * b4.z;             \
        v_.w = 0.299f * r4.w + 0.587f * g4.w + 0.114f * b4.w;             \
    }                                                                     \
    dst = v_;                                                             \
} while (0)

#define STAGE_WRITE(BUF) do {                                             \
    float4* gpw = (float4*)gp[BUF];                                       \
    float4* gtw = (float4*)gt[BUF];                                       \
    float4 w_;                                                            \
    GRAY4S(w_, Ap_r, Ap_g, Ap_b, v0);  gpw[i0] = w_;                      \
    GRAY4S(w_, At_r, At_g, At_b, v0);  gtw[i0] = w_;                      \
    GRAY4S(w_, Bp_r, Bp_g, Bp_b, v1);  gpw[i1] = w_;                      \
    GRAY4S(w_, Bt_r, Bt_g, Bt_b, v1);  gtw[i1] = w_;                      \
    if (act2) {                                                           \
        GRAY4S(w_, Cp_r, Cp_g, Cp_b, v2);  gpw[i2] = w_;                  \
        GRAY4S(w_, Ct_r, Ct_g, Ct_b, v2);  gtw[i2] = w_;                  \
    }                                                                     \
} while (0)

    int   cur  = 0;
    float lsum = 0.0f;

    // ---- prologue: stage tile 0 into buffer 0 (one full-latency wait) ----
    STAGE_LOAD(tt0 * TY);
    STAGE_WRITE(0);

    for (int t = 0; t < NT; ++t) {
        __syncthreads();                          // buf[cur] writes visible
        const bool have = (t + 1 < NT);
        if (have) STAGE_LOAD((tt0 + t + 1) * TY); // issue AFTER barrier
        __builtin_amdgcn_sched_barrier(0);        // loads stay above compute

        // ---- compute tile t from buf[cur] (identical math to R2, proven) --
        {
            const float* gpc = gp[cur];
            const float* gtc = gt[cur];
            const int tx = tid & 63;
            const int ty = tid >> 6;
            #pragma unroll
            for (int ii = 0; ii < TY / 4; ++ii) {
                const int ry = ty + 4 * ii;
                const float* cp = &gpc[ry * LDS_W + tx + 3];
                const float* ct = &gtc[ry * LDS_W + tx + 3];

                float p00 = cp[0],         p01 = cp[1],             p02 = cp[2];
                float p10 = cp[LDS_W],                              p12 = cp[LDS_W + 2];
                float p20 = cp[2*LDS_W],   p21 = cp[2*LDS_W + 1],   p22 = cp[2*LDS_W + 2];
                float ex = (p02 - p00) + 2.0f * (p12 - p10) + (p22 - p20);
                float ey = (p20 - p00) + 2.0f * (p21 - p01) + (p22 - p02);
                float ep = sqrtf(ex * ex + ey * ey);

                float t00 = ct[0],         t01 = ct[1],             t02 = ct[2];
                float t10 = ct[LDS_W],                              t12 = ct[LDS_W + 2];
                float t20 = ct[2*LDS_W],   t21 = ct[2*LDS_W + 1],   t22 = ct[2*LDS_W + 2];
                float fx = (t02 - t00) + 2.0f * (t12 - t10) + (t22 - t20);
                float fy = (t20 - t00) + 2.0f * (t21 - t01) + (t22 - t02);
                float et = sqrtf(fx * fx + fy * fy);

                lsum += fabsf(ep - et);
            }
        }
        __builtin_amdgcn_sched_barrier(0);        // write stays below compute

        if (have) STAGE_WRITE(cur ^ 1);           // vmcnt wait lands here
        cur ^= 1;
    }

    // ---- reduce: wave shuffle -> cross-wave LDS -> one atomic per block ----
    #pragma unroll
    for (int off = 32; off > 0; off >>= 1)
        lsum += __shfl_down(lsum, off, 64);

    if ((tid & 63) == 0) wsum[tid >> 6] = lsum;
    __syncthreads();
    if (tid == 0) {
        const float s = wsum[0] + wsum[1] + wsum[2] + wsum[3];
        const float inv_n = 1.0f / ((float)BATCH * HH * WW);
        atomicAdd(out, s * inv_n);
    }
}

extern "C" void kernel_launch(void* const* d_in, const int* in_sizes, int n_in,
                              void* d_out, int out_size, void* d_ws, size_t ws_size,
                              hipStream_t stream) {
    const float* pred   = (const float*)d_in[0];
    const float* target = (const float*)d_in[1];
    float* out = (float*)d_out;

    // d_out is poisoned 0xAA before every timed launch -> zero it on-stream.
    zero_out_kernel<<<1, 1, 0, stream>>>(out);

    // 8 x-tiles x 4 tile-groups (NT=4 vertical tiles each) x 32 images
    // = 1024 blocks = 4 blocks/CU, 16 waves/CU, 4x39.4KB = 158KB LDS/CU.
    dim3 grid(WW / TX, (HH / TY) / NT, BATCH);
    edge_loss_kernel<<<grid, 256, 0, stream>>>(pred, target, out);
}

// Round 11
// 246.316 us; speedup vs baseline: 1.7106x; 1.6930x over previous
//
#include <hip/hip_runtime.h>

// EdgeLoss: mean |sobel_mag(gray(pred)) - sobel_mag(gray(target))|
// pred/target: (32, 3, 512, 512) fp32, output: scalar fp32.
//
// Session law (fits R2/R5/R6/R8/R9): sustained global-load throughput is
// ~1.6 B/cyc PER WAVE for every barrier-free structure (source-level MLP
// does not change it: R3, R6), barriers halve it (R2: 0.55), and the
// per-CU path reaches >=28 B/cyc when L2/L3 serve re-reads (R8 - the only
// kernel that hit its own roofline). So: BW = occupancy x 1.6 B/cyc, HBM
// floor = 201MB/6.3TB/s = 32us. Lever = occupancy x fewer bytes, in R8's
// exact spill-proof shape (R9/R10 proved held-register staging = scratch).
//
// R12 = R8 with 2 output rows per thread: 4 input rows per 2 output rows
// -> 605MB requested (vs R8's 906), same streaming discipline: static
// fully-unrolled arrays (constant indices only), sequential pred-then-
// target, no LDS staging, no sched_barrier, no pipelining. g[4][6] + e[2][4]
// keeps pressure ~55 VGPR (<=64 -> 8 waves/SIMD). 2048 blocks, 2 trips.
//
// R13: identical resubmit — R12 never ran (GPUAcquisitionTimeout).

#define BATCH 32
#define HH 512
#define WW 512
#define IMG ((size_t)HH * WW)
#define CHUNKS 128                      // float4 chunks per row
#define RPAIRS 256                      // 512 rows / 2 per thread-item
#define TOTAL (BATCH * RPAIRS * CHUNKS) // 1048576 work items
#define GRID 2048                       // x256 thr -> exactly 2 trips

__global__ void zero_out_kernel(float* out) { out[0] = 0.0f; }

__device__ __forceinline__ float gray1(float r, float g, float b) {
    return 0.299f * r + 0.587f * g + 0.114f * b;
}

// Sobel magnitude, same expression structure as R2..R10 (all passed):
// a = row y-1, b = row y, c = row y+1 ; 0=j-1, 1=j, 2=j+1
#define MAG(a0, a1, a2, b0, b2, c0, c1, c2)                              \
    ({ float ex_ = ((a2) - (a0)) + 2.0f * ((b2) - (b0)) + ((c2) - (c0)); \
       float ey_ = ((c0) - (a0)) + 2.0f * ((c1) - (a1)) + ((c2) - (a2)); \
       sqrtf(ex_ * ex_ + ey_ * ey_); })

// Edge magnitudes for 2 rows x 4 px (rows row0,row0+1; cols x0..x0+3).
// g[k][i] = gray of input row (row0-1+k), col (x0-1+i), zero outside image.
// Output row row0   uses g[0..2]; row row0+1 uses g[1..3].
__device__ __forceinline__ void edges2x4(const float* __restrict__ base,
                                         int row0, int x0, bool okl, bool okr,
                                         float e[2][4])
{
    float g[4][6];
    #pragma unroll
    for (int k = 0; k < 4; ++k) {
        const int gy = row0 - 1 + k;
        if ((unsigned)gy < (unsigned)HH) {
            const float* rbase = base + (size_t)gy * WW;
            const float4 mr = *(const float4*)(rbase + x0);
            const float4 mg = *(const float4*)(rbase + IMG + x0);
            const float4 mb = *(const float4*)(rbase + 2 * IMG + x0);
            float lr = 0.f, lg = 0.f, lb = 0.f;
            float rr = 0.f, rg = 0.f, rb = 0.f;
            if (okl) {
                lr = rbase[x0 - 1];
                lg = rbase[IMG + x0 - 1];
                lb = rbase[2 * IMG + x0 - 1];
            }
            if (okr) {
                rr = rbase[x0 + 4];
                rg = rbase[IMG + x0 + 4];
                rb = rbase[2 * IMG + x0 + 4];
            }
            g[k][0] = gray1(lr, lg, lb);       // 0 when !okl (border)
            g[k][1] = gray1(mr.x, mg.x, mb.x);
            g[k][2] = gray1(mr.y, mg.y, mb.y);
            g[k][3] = gray1(mr.z, mg.z, mb.z);
            g[k][4] = gray1(mr.w, mg.w, mb.w);
            g[k][5] = gray1(rr, rg, rb);       // 0 when !okr (border)
        } else {
            #pragma unroll
            for (int i = 0; i < 6; ++i) g[k][i] = 0.f;
        }
    }
    #pragma unroll
    for (int r = 0; r < 2; ++r) {
        #pragma unroll
        for (int j = 0; j < 4; ++j)
            e[r][j] = MAG(g[r][j],     g[r][j + 1],     g[r][j + 2],
                          g[r + 1][j],                  g[r + 1][j + 2],
                          g[r + 2][j], g[r + 2][j + 1], g[r + 2][j + 2]);
    }
}

__global__ __launch_bounds__(256, 4) void edge_loss_kernel(
    const float* __restrict__ pred,
    const float* __restrict__ target,
    float* __restrict__ out)
{
    const int tid = threadIdx.x;
    float lsum = 0.0f;

    for (int idx = blockIdx.x * 256 + tid; idx < TOTAL; idx += GRID * 256) {
        const int img   = idx >> 15;          // 256 rpairs * 128 chunks = 2^15
        const int rp    = (idx >> 7) & 255;
        const int chunk = idx & 127;
        const int row0  = rp << 1;
        const int x0    = chunk << 2;
        const bool okl  = (chunk > 0);
        const bool okr  = (chunk < CHUNKS - 1);

        const float* pb = pred   + (size_t)img * 3 * IMG;
        const float* tb = target + (size_t)img * 3 * IMG;

        float ep[2][4], et[2][4];
        edges2x4(pb, row0, x0, okl, okr, ep);
        edges2x4(tb, row0, x0, okl, okr, et);

        lsum += fabsf(ep[0][0] - et[0][0]) + fabsf(ep[0][1] - et[0][1])
              + fabsf(ep[0][2] - et[0][2]) + fabsf(ep[0][3] - et[0][3])
              + fabsf(ep[1][0] - et[1][0]) + fabsf(ep[1][1] - et[1][1])
              + fabsf(ep[1][2] - et[1][2]) + fabsf(ep[1][3] - et[1][3]);
    }

    // ---- reduce: wave shuffle -> cross-wave LDS -> one atomic per block ----
    #pragma unroll
    for (int off = 32; off > 0; off >>= 1)
        lsum += __shfl_down(lsum, off, 64);

    __shared__ float wsum[4];
    const int lane = tid & 63;
    const int wav  = tid >> 6;
    if (lane == 0) wsum[wav] = lsum;
    __syncthreads();
    if (tid == 0) {
        const float s = wsum[0] + wsum[1] + wsum[2] + wsum[3];
        const float inv_n = 1.0f / ((float)BATCH * HH * WW);
        atomicAdd(out, s * inv_n);
    }
}

extern "C" void kernel_launch(void* const* d_in, const int* in_sizes, int n_in,
                              void* d_out, int out_size, void* d_ws, size_t ws_size,
                              hipStream_t stream) {
    const float* pred   = (const float*)d_in[0];
    const float* target = (const float*)d_in[1];
    float* out = (float*)d_out;

    // d_out is poisoned 0xAA before every timed launch -> zero it on-stream.
    zero_out_kernel<<<1, 1, 0, stream>>>(out);

    edge_loss_kernel<<<dim3(GRID, 1, 1), 256, 0, stream>>>(pred, target, out);
}